// Round 1
// baseline (462.784 us; speedup 1.0000x reference)
//
#include <hip/hip_runtime.h>
#include <stdint.h>

// HunyuanVideo attn block: rmsnorm -> qkv proj -> frame-causal attention -> out proj + residual
// B=1, C=512, T=8, H=W=32 -> S=8192, frame block = 1024.
// Workspace usage: ~58.3 MB (weights bf16 2MB, xn/q/k/v/oat 40MB, attn partials 16MB, ml 128KB).

typedef __bf16 bf16;
typedef __bf16 bf16x8 __attribute__((ext_vector_type(8)));
typedef float f32x4 __attribute__((ext_vector_type(4)));
typedef uint32_t u32;
typedef uint32_t u32x2 __attribute__((ext_vector_type(2)));

#define MFMA16(a, b, c) __builtin_amdgcn_mfma_f32_16x16x32_bf16((a), (b), (c), 0, 0, 0)

__device__ __forceinline__ u32 pack2(float a, float b) {
  union { bf16 h[2]; u32 u; } x;
  x.h[0] = (bf16)a;
  x.h[1] = (bf16)b;
  return x.u;
}

// ---------------- weights fp32 -> bf16 ----------------
__global__ void cvt_w_kernel(const float* __restrict__ a, const float* __restrict__ b,
                             const float* __restrict__ c, const float* __restrict__ d,
                             bf16* __restrict__ out) {
  int i = blockIdx.x * 256 + threadIdx.x;
  const int N = 512 * 512;
  out[i]         = (bf16)a[i];
  out[N + i]     = (bf16)b[i];
  out[2 * N + i] = (bf16)c[i];
  out[3 * N + i] = (bf16)d[i];
}

// ---------------- rmsnorm over C + transpose to [S][C] bf16 ----------------
// x: [C=512][S=8192] f32.  xn[s][c] = x[c][s] * sqrt(C)/max(||x[:,s]||,1e-12) * gamma[c]
__global__ __launch_bounds__(256) void rmsnorm_kernel(const float* __restrict__ x,
                                                      const float* __restrict__ gamma,
                                                      bf16* __restrict__ xn) {
  const int S = 8192;
  __shared__ float sums[4][64];
  int ts = threadIdx.x & 63, tc = threadIdx.x >> 6;
  int s = blockIdx.x * 64 + ts;
  float acc = 0.f;
  for (int c = tc * 128; c < tc * 128 + 128; ++c) {
    float v = x[(size_t)c * S + s];
    acc += v * v;
  }
  sums[tc][ts] = acc;
  __syncthreads();
  float tot = sums[0][ts] + sums[1][ts] + sums[2][ts] + sums[3][ts];
  float kk = 22.62741699796952f / fmaxf(sqrtf(tot), 1e-12f);
  for (int c0 = tc * 128; c0 < tc * 128 + 128; c0 += 8) {
    bf16x8 o;
#pragma unroll
    for (int j = 0; j < 8; ++j) o[j] = (bf16)(x[(size_t)(c0 + j) * S + s] * kk * gamma[c0 + j]);
    *(bf16x8*)(xn + (size_t)s * 512 + c0) = o;
  }
}

// ---------------- NT GEMM: C[m,n] = sum_k A[m,k]*B[n,k], K=512 ----------------
// EPI 0: out bf16 [M][N], += bias[n]     (QKV projections)
// EPI 1: out f32  [M][N], += bias[m] + resid[m*N+n]   (final projection + residual)
template <int EPI>
__global__ __launch_bounds__(256) void gemm_nt_kernel(const bf16* __restrict__ A,
                                                      const bf16* __restrict__ B,
                                                      const float* __restrict__ bias,
                                                      const float* __restrict__ resid,
                                                      void* __restrict__ Cout, int M, int N,
                                                      int nbn) {
  __shared__ bf16 a_lds[128 * 72];
  __shared__ bf16 b_lds[128 * 72];
  const int K = 512;
  int bm = blockIdx.x / nbn, bn = blockIdx.x % nbn;
  int m0 = bm * 128, n0 = bn * 128;
  int tid = threadIdx.x, lane = tid & 63;
  int wid = tid >> 6;
  int wm = (wid >> 1) * 64, wn = (wid & 1) * 64;
  int l15 = lane & 15, l4 = lane >> 4;
  f32x4 acc[4][4];
#pragma unroll
  for (int i = 0; i < 4; ++i)
#pragma unroll
    for (int j = 0; j < 4; ++j) acc[i][j] = (f32x4){0.f, 0.f, 0.f, 0.f};

  for (int k0 = 0; k0 < K; k0 += 64) {
    __syncthreads();
#pragma unroll
    for (int i = 0; i < 4; ++i) {
      int lin = i * 2048 + tid * 8;
      int r = lin >> 6, c = lin & 63;
      *(bf16x8*)(a_lds + r * 72 + c) = *(const bf16x8*)(A + (size_t)(m0 + r) * K + k0 + c);
      *(bf16x8*)(b_lds + r * 72 + c) = *(const bf16x8*)(B + (size_t)(n0 + r) * K + k0 + c);
    }
    __syncthreads();
#pragma unroll
    for (int kk = 0; kk < 2; ++kk) {
      bf16x8 af[4], bfr[4];
#pragma unroll
      for (int i = 0; i < 4; ++i)
        af[i] = *(bf16x8*)(a_lds + (wm + i * 16 + l15) * 72 + kk * 32 + l4 * 8);
#pragma unroll
      for (int j = 0; j < 4; ++j)
        bfr[j] = *(bf16x8*)(b_lds + (wn + j * 16 + l15) * 72 + kk * 32 + l4 * 8);
#pragma unroll
      for (int i = 0; i < 4; ++i)
#pragma unroll
        for (int j = 0; j < 4; ++j) acc[i][j] = MFMA16(af[i], bfr[j], acc[i][j]);
    }
  }
#pragma unroll
  for (int i = 0; i < 4; ++i)
#pragma unroll
    for (int j = 0; j < 4; ++j) {
      int col = n0 + wn + j * 16 + l15;
#pragma unroll
      for (int r = 0; r < 4; ++r) {
        int row = m0 + wm + i * 16 + l4 * 4 + r;
        float v = acc[i][j][r];
        if (EPI == 0) {
          v += bias[col];
          ((bf16*)Cout)[(size_t)row * N + col] = (bf16)v;
        } else {
          size_t idx = (size_t)row * N + col;
          ((float*)Cout)[idx] = v + bias[row] + resid[idx];
        }
      }
    }
}

// ---------------- flash attention with frame-block causal mask ----------------
// grid 512: 256 q-tiles (32 rows) x 2 kv-halves. 128 threads = 2 waves, one 16-row band each.
// Swapped QK^T: S^T[kv][q] = mfma(A=K_frag, B=Q_frag) so softmax per q is column-local (lane&15).
// PV: O^T[d][q] = mfma(A=V^T_frag, B=P_frag); V staged in LDS as kv-pair-packed dwords [d][kvpair].
// Writes unnormalized partial O (bf16) + (m,l) per row; combine kernel merges the two halves.
__global__ __launch_bounds__(128, 1) void attn_kernel(const bf16* __restrict__ Qg,
                                                      const bf16* __restrict__ Kg,
                                                      const bf16* __restrict__ Vg,
                                                      bf16* __restrict__ Opart,
                                                      float2* __restrict__ mlbuf) {
  const float SC2 = 1.4426950408889634f / 22.627416997969522f;  // (1/sqrt(512))*log2(e)
  __shared__ bf16 k_lds[32 * 520];     // K tile [32 kv][512+8 pad]
  __shared__ u32 v_lds[512 * 20];      // V^T packed: [d][16 kvpair + 4 pad] dwords
  __shared__ u32 p_lds[2][16 * 20];    // per band: P [16 q][16 kvpair + 4 pad] dwords

  int b = blockIdx.x;
  int h = b >> 8;          // kv half
  int bb = b & 255;
  int qt = (bb & 7) + (bb >> 3) * 8;  // spread frames across XCDs (b%8 = XCD)
  int q0 = qt * 32;
  int f = q0 >> 10;
  int htiles = (f + 1) * 16;  // tiles of 32 kv per half
  int t0 = h * htiles, t1 = t0 + htiles;

  int tid = threadIdx.x;
  int wid = tid >> 6;
  int lane = tid & 63;
  int l15 = lane & 15, l4 = lane >> 4;
  int vm = tid & 15, vo = tid >> 4;

  int qrow = q0 + wid * 16 + l15;
  bf16x8 qreg[16];
#pragma unroll
  for (int ks = 0; ks < 16; ++ks)
    qreg[ks] = *(const bf16x8*)(Qg + (size_t)qrow * 512 + ks * 32 + l4 * 8);

  f32x4 oacc[32];
#pragma unroll
  for (int i = 0; i < 32; ++i) oacc[i] = (f32x4){0.f, 0.f, 0.f, 0.f};
  float m2 = -1e30f, lsum = 0.f;

  for (int t = t0; t < t1; ++t) {
    int kv0 = t * 32;
    __syncthreads();
    // stage K tile [32][512]
#pragma unroll
    for (int i = 0; i < 16; ++i) {
      int lin = i * 1024 + tid * 8;
      int r = lin >> 9, c = lin & 511;
      *(bf16x8*)(k_lds + r * 520 + c) = *(const bf16x8*)(Kg + (size_t)(kv0 + r) * 512 + c);
    }
    // stage V transposed+packed: dword[d][m] = (V[2m][d], V[2m+1][d])
#pragma unroll
    for (int j = 0; j < 8; ++j) {
      int dbase = vo * 8 + j * 64;
      union { bf16x8 v; unsigned short s[8]; } r0, r1;
      r0.v = *(const bf16x8*)(Vg + (size_t)(kv0 + 2 * vm) * 512 + dbase);
      r1.v = *(const bf16x8*)(Vg + (size_t)(kv0 + 2 * vm + 1) * 512 + dbase);
#pragma unroll
      for (int ii = 0; ii < 8; ++ii)
        v_lds[(dbase + ii) * 20 + vm] = (u32)r0.s[ii] | ((u32)r1.s[ii] << 16);
    }
    __syncthreads();

    // QK^T -> S^T[kv 32][q 16]
    f32x4 sacc0 = {0.f, 0.f, 0.f, 0.f}, sacc1 = {0.f, 0.f, 0.f, 0.f};
#pragma unroll
    for (int ks = 0; ks < 16; ++ks) {
      bf16x8 a0 = *(bf16x8*)(k_lds + l15 * 520 + ks * 32 + l4 * 8);
      bf16x8 a1 = *(bf16x8*)(k_lds + (l15 + 16) * 520 + ks * 32 + l4 * 8);
      sacc0 = MFMA16(a0, qreg[ks], sacc0);
      sacc1 = MFMA16(a1, qreg[ks], sacc1);
    }

    // online softmax for column q = l15 (values for this q live in lanes q,q+16,q+32,q+48)
    float pmax = -1e30f;
#pragma unroll
    for (int r = 0; r < 4; ++r) {
      pmax = fmaxf(pmax, sacc0[r]);
      pmax = fmaxf(pmax, sacc1[r]);
    }
    pmax = fmaxf(pmax, __shfl_xor(pmax, 16));
    pmax = fmaxf(pmax, __shfl_xor(pmax, 32));
    pmax *= SC2;
    bool skip = (m2 > -1e29f) && (__all(pmax <= m2 + 11.5415603f) != 0);  // defer-max THR=8
    float m2n = skip ? m2 : fmaxf(m2, pmax);
    float p[8];
    float psum = 0.f;
#pragma unroll
    for (int r = 0; r < 4; ++r) {
      p[r] = exp2f(sacc0[r] * SC2 - m2n);
      p[4 + r] = exp2f(sacc1[r] * SC2 - m2n);
      psum += p[r] + p[4 + r];
    }
    psum += __shfl_xor(psum, 16);
    psum += __shfl_xor(psum, 32);
    if (!skip) {
      float corr = exp2f(m2 - m2n);
      lsum = lsum * corr;
#pragma unroll
      for (int i = 0; i < 32; ++i) oacc[i] *= corr;
      m2 = m2n;
    }
    lsum += psum;

    // P -> p_lds[q][kv] (packed dwords). lane holds q=l15, kv=l4*4+r (+16 for sacc1)
    u32* prow = &p_lds[wid][l15 * 20];
    *(u32x2*)(prow + l4 * 2) = (u32x2){pack2(p[0], p[1]), pack2(p[2], p[3])};
    *(u32x2*)(prow + l4 * 2 + 8) = (u32x2){pack2(p[4], p[5]), pack2(p[6], p[7])};

    // PV: O^T[d][q] += V^T[d][kv] * P[kv][q]
    bf16x8 pfrag = *(bf16x8*)(prow + l4 * 4);
#pragma unroll
    for (int df = 0; df < 32; ++df) {
      bf16x8 vf = *(bf16x8*)(&v_lds[(df * 16 + l15) * 20 + l4 * 4]);
      oacc[df] = MFMA16(vf, pfrag, oacc[df]);
    }
  }

  // write unnormalized partial (lane holds q=l15, d = df*16 + l4*4 + reg)
  int qr = q0 + wid * 16 + l15;
  bf16* op = Opart + (size_t)h * 8192 * 512 + (size_t)qr * 512;
#pragma unroll
  for (int df = 0; df < 32; ++df) {
    int d = df * 16 + l4 * 4;
    u32x2 pk2 = {pack2(oacc[df][0], oacc[df][1]), pack2(oacc[df][2], oacc[df][3])};
    *(u32x2*)(op + d) = pk2;
  }
  if (l4 == 0) mlbuf[h * 8192 + qr] = make_float2(m2, lsum);
}

// ---------------- merge the two kv-halves ----------------
__global__ void combine_kernel(const bf16* __restrict__ Op, const float2* __restrict__ ml,
                               bf16* __restrict__ O) {
  int i = blockIdx.x * 256 + threadIdx.x;  // 8192 rows * 64 chunks
  int row = i >> 6, dc = (i & 63) * 8;
  float2 a = ml[row], c = ml[8192 + row];
  float mm = fmaxf(a.x, c.x);
  float w0 = exp2f(a.x - mm), w1 = exp2f(c.x - mm);
  float denom = 1.f / (w0 * a.y + w1 * c.y);
  bf16x8 o0 = *(const bf16x8*)(Op + (size_t)row * 512 + dc);
  bf16x8 o1 = *(const bf16x8*)(Op + (size_t)8192 * 512 + (size_t)row * 512 + dc);
  bf16x8 r;
#pragma unroll
  for (int j = 0; j < 8; ++j) r[j] = (bf16)(((float)o0[j] * w0 + (float)o1[j] * w1) * denom);
  *(bf16x8*)(O + (size_t)row * 512 + dc) = r;
}

extern "C" void kernel_launch(void* const* d_in, const int* in_sizes, int n_in, void* d_out,
                              int out_size, void* d_ws, size_t ws_size, hipStream_t stream) {
  (void)in_sizes; (void)n_in; (void)out_size; (void)ws_size;
  const float* x = (const float*)d_in[0];
  const float* gamma = (const float*)d_in[1];
  const float* wq = (const float*)d_in[2];
  const float* bq = (const float*)d_in[3];
  const float* wk = (const float*)d_in[4];
  const float* bk = (const float*)d_in[5];
  const float* wv = (const float*)d_in[6];
  const float* bv = (const float*)d_in[7];
  const float* wo = (const float*)d_in[8];
  const float* bo = (const float*)d_in[9];

  const size_t SC = (size_t)8192 * 512;
  bf16* wq_b = (bf16*)d_ws;          // 4 x 256K bf16 = 2MB
  bf16* wk_b = wq_b + 262144;
  bf16* wv_b = wk_b + 262144;
  bf16* wo_b = wv_b + 262144;
  bf16* xn = wo_b + 262144;          // 8MB each below
  bf16* q = xn + SC;
  bf16* k = q + SC;
  bf16* v = k + SC;
  bf16* oat = v + SC;
  bf16* opart = oat + SC;            // 2 x 8MB partials
  float2* ml = (float2*)(opart + 2 * SC);  // 128KB

  cvt_w_kernel<<<1024, 256, 0, stream>>>(wq, wk, wv, wo, wq_b);
  rmsnorm_kernel<<<128, 256, 0, stream>>>(x, gamma, xn);
  gemm_nt_kernel<0><<<256, 256, 0, stream>>>(xn, wq_b, bq, nullptr, q, 8192, 512, 4);
  gemm_nt_kernel<0><<<256, 256, 0, stream>>>(xn, wk_b, bk, nullptr, k, 8192, 512, 4);
  gemm_nt_kernel<0><<<256, 256, 0, stream>>>(xn, wv_b, bv, nullptr, v, 8192, 512, 4);
  attn_kernel<<<512, 128, 0, stream>>>(q, k, v, opart, ml);
  combine_kernel<<<2048, 256, 0, stream>>>(opart, ml, oat);
  gemm_nt_kernel<1><<<256, 256, 0, stream>>>(wo_b, oat, bo, x, d_out, 512, 8192, 64);
}